// Round 5
// baseline (131.253 us; speedup 1.0000x reference)
//
#include <hip/hip_runtime.h>

#define K_CW 256
#define PPT 4           // points per thread
#define NH 2            // split-K halves
#define KH (K_CW / NH)  // 128 k per half

// ws layout: c4[256] (float4) at pk[0..1023], csq[256] (float) at pk[1024..1279].
// csq uses numpy rounding: ((c0*c0 + c1*c1) + c2*c2) + c3*c3 (sequential adds
// of rounded squares).
__global__ void vq_pack_kernel(const float* __restrict__ tlut, float* __restrict__ pk) {
    int k = threadIdx.x;  // 256 threads, 1 block
    float c0 = tlut[k * 4 + 0];
    float c1 = tlut[k * 4 + 1];
    float c2 = tlut[k * 4 + 2];
    float c3 = tlut[k * 4 + 3];
    float s = __fadd_rn(__fadd_rn(__fadd_rn(__fmul_rn(c0, c0), __fmul_rn(c1, c1)),
                                  __fmul_rn(c2, c2)),
                        __fmul_rn(c3, c3));
    reinterpret_cast<float4*>(pk)[k] = make_float4(c0, c1, c2, c3);
    pk[1024 + k] = s;
}

__global__ __launch_bounds__(512, 8) void vq_argmin_kernel(
    const float* __restrict__ X,
    const float* __restrict__ tlut,
    const float* __restrict__ pk,
    float* __restrict__ outX,   // [B,4] reconstruction
    float* __restrict__ outS,   // [B] state, stored as float
    int B) {
    // split-K x2: half q scans k in [128q, 128q+128) on the same 4 points.
    // 1024 blocks x 512 thr = 8192 waves = 32 waves/CU, all resident, one round.
    //
    // Codebook fetch via VECTOR global loads (not s_load): VMEM returns are
    // covered by counted vmcnt(N) partial waits, so the compiler can pipeline
    // loads across k-steps without the full lgkmcnt(0) drains that the
    // out-of-order scalar path forces. Wave-uniform address -> one L1
    // transaction, broadcast; pk (5 KB) is L1-resident. Per-k addressing is a
    // 13-bit immediate offset off a hoisted base -> zero per-k VALU.
    __shared__ float sd[PPT][256];  // upper half's bestd (separate b32 arrays:
    __shared__ int   si[PPT][256];  // 2 lanes/bank = conflict-free, r4-verified)

    const int t = threadIdx.x;
    const int tt = t & 255;
    const int q = t >> 8;  // 0 or 1, wave-uniform (wave = 64 consecutive threads)
    const int kbase = __builtin_amdgcn_readfirstlane(q << 7);  // 0 or 128

    const int g = blockIdx.x * 256 + tt;   // point-group id
    const int stride = B / PPT;            // strided points -> coalesced

    const float4* __restrict__ X4 = reinterpret_cast<const float4*>(X);
    const float4* __restrict__ T4 = reinterpret_cast<const float4*>(tlut);
    const float4* __restrict__ C4 = reinterpret_cast<const float4*>(pk);
    const float*  __restrict__ CS = pk + 1024;

    // Opaque zero in a VGPR: forces the codebook index to be non-provably-
    // uniform so the compiler emits global_load (VMEM) instead of s_load.
    int vz;
    asm("v_mov_b32 %0, 0" : "=v"(vz));

    float x0[PPT], x1[PPT], x2[PPT], x3[PPT], xsq[PPT], bestd[PPT];
    int besti[PPT];

    #pragma unroll
    for (int i = 0; i < PPT; ++i) {
        const float4 xv = X4[g + i * stride];
        x0[i] = xv.x; x1[i] = xv.y; x2[i] = xv.z; x3[i] = xv.w;
        // x_sq with numpy rounding: sequential adds of rounded squares
        xsq[i] = __fadd_rn(__fadd_rn(__fadd_rn(__fmul_rn(xv.x, xv.x), __fmul_rn(xv.y, xv.y)),
                                     __fmul_rn(xv.z, xv.z)),
                           __fmul_rn(xv.w, xv.w));
        bestd[i] = __builtin_inff();
        besti[i] = kbase;
    }

    const int kb = kbase + vz;  // VGPR base index, hoisted into the address base

    #pragma unroll 16
    for (int kk = 0; kk < KH; ++kk) {
        const int k = kbase + kk;          // exact index for argmin bookkeeping
        const float4 c = C4[kb + kk];      // global_load_dwordx4, imm offset kk*16
        const float cs = CS[kb + kk];      // global_load_dword,   imm offset kk*4
        #pragma unroll
        for (int i = 0; i < PPT; ++i) {
            // cross: numpy einsum `accum += a*b` with fp-contract -> ascending FMA chain
            float cross = __fmul_rn(x0[i], c.x);
            cross = __fmaf_rn(x1[i], c.y, cross);
            cross = __fmaf_rn(x2[i], c.z, cross);
            cross = __fmaf_rn(x3[i], c.w, cross);
            // (x_sq - 2*cross) + c_sq ; fma(-2,cross,xsq) == rn(xsq - rn(2*cross)) exactly
            float t2 = __fmaf_rn(-2.0f, cross, xsq[i]);
            float d = __fadd_rn(t2, cs);
            // argmin, first occurrence (strict <), ascending k
            besti[i] = (d < bestd[i]) ? k : besti[i];
            bestd[i] = fminf(d, bestd[i]);
        }
    }

    if (q == 1) {
        #pragma unroll
        for (int i = 0; i < PPT; ++i) { sd[i][tt] = bestd[i]; si[i][tt] = besti[i]; }
    }
    __syncthreads();
    if (q == 0) {
        // merge: upper half (larger k) wins only on strict '<' -> np.argmin
        // first-occurrence preserved.
        #pragma unroll
        for (int i = 0; i < PPT; ++i) {
            const float od = sd[i][tt];
            const int   oi = si[i][tt];
            if (od < bestd[i]) { bestd[i] = od; besti[i] = oi; }
        }
        #pragma unroll
        for (int i = 0; i < PPT; ++i) {
            const int p = g + i * stride;
            reinterpret_cast<float4*>(outX)[p] = T4[besti[i]];  // tlut is L1-resident
            outS[p] = (float)besti[i];
        }
    }
}

extern "C" void kernel_launch(void* const* d_in, const int* in_sizes, int n_in,
                              void* d_out, int out_size, void* d_ws, size_t ws_size,
                              hipStream_t stream) {
    const float* X    = (const float*)d_in[0];   // [B,4]
    const float* tlut = (const float*)d_in[1];   // [256,4]
    const int B = in_sizes[0] / 4;

    float* outX = (float*)d_out;          // first B*4 floats: hatX
    float* outS = outX + (size_t)B * 4;   // next B floats: state (as float)

    float* pk = (float*)d_ws;             // 1280 floats: c4[256] + csq[256]

    vq_pack_kernel<<<1, 256, 0, stream>>>(tlut, pk);

    const int groups = B / PPT;           // 262144 point-groups
    const int grid = groups / 256;        // 1024 blocks of 512 threads
    vq_argmin_kernel<<<grid, 512, 0, stream>>>(X, tlut, pk, outX, outS, B);
}

// Round 7
// 122.019 us; speedup vs baseline: 1.0757x; 1.0757x over previous
//
#include <hip/hip_runtime.h>

#define K_CW 256
#define PPT 4           // points per thread
#define NH 2            // split-K halves
#define KH (K_CW / NH)  // 128 k per half

// Single fused kernel. Codebook staged in LDS, entry stride 32 B:
// {c0,c1,c2,c3,csq,pad,pad,pad}. Read with ONE fixed base VGPR and
// compile-time immediate offsets -> per-k cost is 2 DS issue slots
// (ds_read_b128 + ds_read_b32), ZERO address VALU. DS returns are in-order
// -> compiler emits partial lgkmcnt(N) waits and pipelines ~7 k-steps ahead
// (15-op lgkm queue), unlike the SMEM path whose out-of-order returns force
// full lgkmcnt(0) drain cliffs (the measured ~29% VALU-idle in r0/r3/r4).
__global__ __launch_bounds__(512, 8) void vq_argmin_kernel(
    const float* __restrict__ X,
    const float* __restrict__ tlut,
    float* __restrict__ outX,   // [B,4] reconstruction
    float* __restrict__ outS,   // [B] state, stored as float
    int B) {
    __shared__ float scb[K_CW * 8];   // 8 KB codebook, stride 8 floats (32 B)
    __shared__ float sd[PPT][256];    // 4 KB: upper half's bestd (b32 arrays:
    __shared__ int   si[PPT][256];    // 4 KB: 2 lanes/bank = conflict-free, r4-verified)

    const int t = threadIdx.x;
    const int tt = t & 255;
    const int q = t >> 8;  // 0 or 1, wave-uniform (wave = 64 consecutive threads)
    const int kbase = __builtin_amdgcn_readfirstlane(q << 7);  // 0 or 128

    // Stage codebook: thread k (< 256) owns codeword k. csq uses numpy
    // rounding: ((c0*c0 + c1*c1) + c2*c2) + c3*c3 (sequential rounded adds).
    if (t < 256) {
        const float4 cv = reinterpret_cast<const float4*>(tlut)[t];
        const float s = __fadd_rn(__fadd_rn(__fadd_rn(__fmul_rn(cv.x, cv.x),
                                                      __fmul_rn(cv.y, cv.y)),
                                            __fmul_rn(cv.z, cv.z)),
                                  __fmul_rn(cv.w, cv.w));
        reinterpret_cast<float4*>(scb)[t * 2] = cv;   // bytes [t*32, t*32+16)
        scb[t * 8 + 4] = s;                            // byte t*32+16
    }

    const int g = blockIdx.x * 256 + tt;   // point-group id
    const int stride = B / PPT;            // strided points -> coalesced

    const float4* __restrict__ X4 = reinterpret_cast<const float4*>(X);
    const float4* __restrict__ T4 = reinterpret_cast<const float4*>(tlut);

    float x0[PPT], x1[PPT], x2[PPT], x3[PPT], xsq[PPT], bestd[PPT];
    int besti[PPT];

    #pragma unroll
    for (int i = 0; i < PPT; ++i) {
        const float4 xv = X4[g + i * stride];
        x0[i] = xv.x; x1[i] = xv.y; x2[i] = xv.z; x3[i] = xv.w;
        // x_sq with numpy rounding: sequential adds of rounded squares
        xsq[i] = __fadd_rn(__fadd_rn(__fadd_rn(__fmul_rn(xv.x, xv.x), __fmul_rn(xv.y, xv.y)),
                                     __fmul_rn(xv.z, xv.z)),
                           __fmul_rn(xv.w, xv.w));
        bestd[i] = __builtin_inff();
        besti[i] = kbase;
    }

    __syncthreads();

    // Half-q base: 128 entries * 8 floats. Single base VGPR; all reads below
    // are base + immediate (max offset 128*32 = 4 KB < 64 KB DS imm field).
    const float* __restrict__ cb = scb + (q << 10);

    #pragma unroll 16
    for (int kk = 0; kk < KH; ++kk) {
        const int k = kbase + kk;          // index for argmin bookkeeping
        const float4 c = *reinterpret_cast<const float4*>(cb + kk * 8);  // ds_read_b128, broadcast
        const float cs = cb[kk * 8 + 4];                                 // ds_read_b32,  broadcast
        #pragma unroll
        for (int i = 0; i < PPT; ++i) {
            // cross: numpy einsum `accum += a*b` with fp-contract -> ascending FMA chain
            float cross = __fmul_rn(x0[i], c.x);
            cross = __fmaf_rn(x1[i], c.y, cross);
            cross = __fmaf_rn(x2[i], c.z, cross);
            cross = __fmaf_rn(x3[i], c.w, cross);
            // (x_sq - 2*cross) + c_sq ; fma(-2,cross,xsq) == rn(xsq - rn(2*cross)) exactly
            float t2 = __fmaf_rn(-2.0f, cross, xsq[i]);
            float d = __fadd_rn(t2, cs);
            // argmin, first occurrence (strict <), ascending k
            besti[i] = (d < bestd[i]) ? k : besti[i];
            bestd[i] = fminf(d, bestd[i]);
        }
    }

    if (q == 1) {
        #pragma unroll
        for (int i = 0; i < PPT; ++i) { sd[i][tt] = bestd[i]; si[i][tt] = besti[i]; }
    }
    __syncthreads();
    if (q == 0) {
        // merge: upper half (larger k) wins only on strict '<' -> np.argmin
        // first-occurrence preserved.
        #pragma unroll
        for (int i = 0; i < PPT; ++i) {
            const float od = sd[i][tt];
            const int   oi = si[i][tt];
            if (od < bestd[i]) { bestd[i] = od; besti[i] = oi; }
        }
        #pragma unroll
        for (int i = 0; i < PPT; ++i) {
            const int p = g + i * stride;
            reinterpret_cast<float4*>(outX)[p] = T4[besti[i]];  // tlut is L1-resident
            outS[p] = (float)besti[i];
        }
    }
}

extern "C" void kernel_launch(void* const* d_in, const int* in_sizes, int n_in,
                              void* d_out, int out_size, void* d_ws, size_t ws_size,
                              hipStream_t stream) {
    const float* X    = (const float*)d_in[0];   // [B,4]
    const float* tlut = (const float*)d_in[1];   // [256,4]
    const int B = in_sizes[0] / 4;

    float* outX = (float*)d_out;          // first B*4 floats: hatX
    float* outS = outX + (size_t)B * 4;   // next B floats: state (as float)

    const int groups = B / PPT;           // 262144 point-groups
    const int grid = groups / 256;        // 1024 blocks of 512 threads
    vq_argmin_kernel<<<grid, 512, 0, stream>>>(X, tlut, outX, outS, B);
}